// Round 6
// baseline (237.871 us; speedup 1.0000x reference)
//
#include <hip/hip_runtime.h>

// Dense MHA per head: B=2, T=2048, K=2048, H=16, D=128, fp32 in/out, bf16 MFMA.
// Round 13: M=64 per wave -- halve LDS bytes per MFMA FLOP.
//   r12 post-mortem: 2 blocks/CU neutral (105us) -> barrier-lockstep theory
//   refuted. Real limit: M=32 structure reads 1 LDS byte per 32 FLOP; at
//   ds_read_b128 ~85 B/cyc the LDS roofline is ~850 TF (m214's plateau too);
//   we are at 667 = 78% of it. Only fix: more register reuse per LDS read.
//   M=64/wave (tiles A,B): each K-frag read feeds 4 QK MFMAs, each V-frag
//   read feeds 2 PV MFMAs. LDS/CU-iter 256->128KB (~1540 cyc) < matrix
//   (2066 cyc) -> matrix-bound regime. 1024 waves total -> 4-wave blocks,
//   grid 256, 1 block/CU, 1 wave/SIMD; SM(A) overlaps QK(B) in-flight,
//   V reads shared by A+B PV (SM(B) before PV loop). launch_bounds(256,1)
//   relaxes regalloc (acc+s in AGPRs, ~140 VGPR).
// Workspace (fragment-ordered bf16):
//   kf[bh][kt64][ktile(2)][dchunk(8)][lane(64)][8]  (QK A-frag order)
//   vf[bh][kt64][kc(4)][ntile(4)][lane(64)][8]      (PV B-frag order)
// Fallback (ws too small): round-4 kernel (reads raw K/V, passing).

#define T_   2048
#define KLEN 2048
#define H_   16
#define D_   128
#define BH_  32
#define NT_  (KLEN / 64)

typedef unsigned short u16;
typedef short bf16x8 __attribute__((ext_vector_type(8), may_alias));
typedef float f32x4 __attribute__((ext_vector_type(4)));
typedef float f32x8 __attribute__((ext_vector_type(8), may_alias));
typedef float f32x16 __attribute__((ext_vector_type(16)));
typedef unsigned int u32a __attribute__((may_alias));
typedef u16 u16a __attribute__((may_alias));

__device__ __forceinline__ u16 f2bf(float f) {
    unsigned int u = __builtin_bit_cast(unsigned int, f);
    u += 0x7fffu + ((u >> 16) & 1u);   // RNE
    return (u16)(u >> 16);
}
// packed f32x2 -> bf16x2 (RNE), lo = a, hi = b. One VALU op.
__device__ __forceinline__ unsigned int pk2(float a, float b) {
    unsigned int r;
    asm("v_cvt_pk_bf16_f32 %0, %1, %2" : "=v"(r) : "v"(a), "v"(b));
    return r;
}
// v_permlane32_swap_b32: a.hi-lanes <-> b.lo-lanes.
// After: a = {a.lo, b.lo(shifted to hi)}, b = {a.hi(shifted to lo), b.hi}.
__device__ __forceinline__ void pl_swap(unsigned int& a, unsigned int& b) {
    asm("v_permlane32_swap_b32 %0, %1" : "+v"(a), "+v"(b));
}

// async 16B/lane global->LDS: gptr per-lane, LDS dest = uniform base + lane*16
__device__ __forceinline__ void async_cp16(const void* g, void* l) {
    __builtin_amdgcn_global_load_lds(
        (const __attribute__((address_space(1))) unsigned int*)g,
        (__attribute__((address_space(3))) unsigned int*)l, 16, 0, 0);
}

#define FR_ELEMS ((size_t)KLEN * D_)                  /* 262144 per bh */
#define WS_NEED  (2 * BH_ * FR_ELEMS * sizeof(u16))   /* 33.6 MB       */
#define SM_BUF   32768                                /* K 16KB + V 16KB */

// ---------------- fused prep: one block per (bh, kt64) ----------------
// K: QK A-frag (32x32x16): octet (ktile,dchunk,lane) holds
//   K[kt64*64 + ktile*32 + (l&31)][dchunk*16 + (l>>5)*8 + j], linear out.
// V: PV B-frag (32x32x16): octet (kc,ntile,lane) holds
//   V[kt64*64 + kc*16 + (l>>5)*8 + j][ntile*32 + (l&31)], via LDS transpose.
__global__ __launch_bounds__(256)
void prep_fused(const float* __restrict__ k_g, const float* __restrict__ v_g,
                u16* __restrict__ kf, u16* __restrict__ vf) {
    __shared__ __align__(16) unsigned char smk[16384];
    __shared__ __align__(16) unsigned char smv[16384];
    const int kt64 = blockIdx.x & 31;
    const int bh   = blockIdx.x >> 5;
    const int b = bh >> 4, h = bh & 15;
    const int tid = threadIdx.x;

    // ---- K stage: 4 consecutive rows per wave (512B segments), bf16 pack,
    //      LDS row = key*256B, 16B granule XOR-swizzled by (row & 15).
    {
        const float* kbase = k_g + ((size_t)(b * KLEN + kt64 * 64) * H_ + h) * D_;
        #pragma unroll
        for (int i = 0; i < 4; ++i) {
            const int gid  = tid + 256 * i;
            const int row  = gid >> 4;          // 0..63 tile-local key
            const int col8 = gid & 15;          // d-octet index
            f32x8 kv = *(const f32x8*)(kbase + (size_t)row * (H_ * D_) + col8 * 8);
            uint4 w;
            w.x = pk2(kv[0], kv[1]); w.y = pk2(kv[2], kv[3]);
            w.z = pk2(kv[4], kv[5]); w.w = pk2(kv[6], kv[7]);
            *(uint4*)(smk + row * 256 + ((col8 ^ (row & 15)) * 16)) = w;
        }
    }
    // ---- V stage: transposed into smv (r10-verified XOR scheme)
    {
        const float* vbase = v_g + ((size_t)b * KLEN * H_ + h) * D_;
        const int sc0 = tid & 15;
        const int spr = tid >> 4;
        #pragma unroll
        for (int rr = 0; rr < 2; ++rr) {
            const int r0 = 2 * (spr + 16 * rr);            // even tile-local key
            const float* vp = vbase + (size_t)(kt64 * 64 + r0) * (H_ * D_) + sc0 * 8;
            f32x8 va = *(const f32x8*)vp;
            f32x8 vb = *(const f32x8*)(vp + H_ * D_);
            const int g_hi = r0 >> 3;
            const int woff = (r0 & 7) * 2;
            #pragma unroll
            for (int j = 0; j < 8; ++j) {
                const int d = sc0 * 8 + j;
                const int g = g_hi ^ ((d ^ (d >> 3)) & 7);
                *(u32a*)(smv + d * 128 + g * 16 + woff) = pk2(va[j], vb[j]);
            }
        }
    }
    __syncthreads();
    // ---- K readout -> kf (16B/thread, fully coalesced)
    {
        u16* obase = kf + (size_t)bh * FR_ELEMS + (size_t)kt64 * 8192;
        #pragma unroll
        for (int i = 0; i < 4; ++i) {
            const int gid    = tid + 256 * i;    // 0..1023 octets
            const int lane   = gid & 63;
            const int dchunk = (gid >> 6) & 7;
            const int ktile  = gid >> 9;
            const int key  = ktile * 32 + (lane & 31);
            const int col8 = dchunk * 2 + (lane >> 5);
            uint4 w = *(const uint4*)(smk + key * 256 + ((col8 ^ (key & 15)) * 16));
            *(uint4*)(obase + (size_t)gid * 8) = w;
        }
    }
    // ---- V readout -> vf (r10-verified)
    {
        u16* obase = vf + (size_t)bh * FR_ELEMS;
        #pragma unroll
        for (int i = 0; i < 4; ++i) {
            const int gid   = tid + 256 * i;
            const int lane  = gid & 63;
            const int ntile = (gid >> 6) & 3;
            const int kc    = (gid >> 8) & 3;
            const int key0  = kc * 16 + (lane >> 5) * 8;   // tile-local, %8==0
            const int d     = ntile * 32 + (lane & 31);
            const int g     = (key0 >> 3) ^ ((d ^ (d >> 3)) & 7);
            uint4 w = *(const uint4*)(smv + d * 128 + g * 16);
            *(uint4*)(obase + ((size_t)(kt64 * 16 + kc * 4 + ntile) * 64 + lane) * 8) = w;
        }
    }
}

// ---------------- main kernel: swapped-QK 32x32, M=64/wave, in-register softmax --

struct PA2 { bf16x8 f0, f1; };   // A-frags for two 16-key PV chunks

__device__ __forceinline__ PA2 softmax_pack(f32x16 st, float kexp, float& lacc) {
    float p[16];
    #pragma unroll
    for (int r = 0; r < 16; ++r) p[r] = exp2f(st[r] * kexp);
    lacc += (((p[0] + p[1]) + (p[2] + p[3])) + ((p[4] + p[5]) + (p[6] + p[7])))
          + (((p[8] + p[9]) + (p[10] + p[11])) + ((p[12] + p[13]) + (p[14] + p[15])));
    // reg r holds P[q=lane&31][key kl=(r&3)+8*(r>>2)+4*half] (m74/m101 C-layout).
    // A-frag needs lane(half,q): P[q][k = half*8 + j]. Pack pairs then swap
    // halves: out_a = {a.lo, b.lo}, out_b = {a.hi, b.hi} (see pl_swap).
    unsigned int a0 = pk2(p[0], p[1]),   b0 = pk2(p[4], p[5]);
    unsigned int a1 = pk2(p[2], p[3]),   b1 = pk2(p[6], p[7]);
    unsigned int a2 = pk2(p[8], p[9]),   b2 = pk2(p[12], p[13]);
    unsigned int a3 = pk2(p[10], p[11]), b3 = pk2(p[14], p[15]);
    pl_swap(a0, b0); pl_swap(a1, b1); pl_swap(a2, b2); pl_swap(a3, b3);
    uint4 w0; w0.x = a0; w0.y = a1; w0.z = b0; w0.w = b1;   // keys 0..15
    uint4 w1; w1.x = a2; w1.y = a3; w1.z = b2; w1.w = b3;   // keys 16..31
    PA2 r;
    r.f0 = __builtin_bit_cast(bf16x8, w0);
    r.f1 = __builtin_bit_cast(bf16x8, w1);
    return r;
}

__global__ __launch_bounds__(256, 1)
void gqa_fa7(const float* __restrict__ q_g, const u16* __restrict__ kf,
             const u16* __restrict__ vf, float* __restrict__ o_g) {
    __shared__ __align__(16) unsigned char smem[2 * SM_BUF];   // 64 KB

    const int lane = threadIdx.x & 63;
    const int wave = threadIdx.x >> 6;        // 0..3
    const int half = lane >> 5;
    const int col  = lane & 31;

    // grid 256 = 1 block/CU; XCD swizzle: bh = xcd*4 + j, 8 qt blocks per bh
    const int blk = blockIdx.x;
    const int bh  = (blk & 7) * 4 + (blk >> 6);
    const int qt  = (blk >> 3) & 7;
    const int b = bh >> 4, h = bh & 15;

    const int q0 = qt * 256 + wave * 64;      // this wave: rows q0 .. q0+63
                                              // tile A = q0.., tile B = q0+32..

    // Q B-frags (32x32x16): lane holds Q[row+col][dchunk*16 + half*8 + j]
    bf16x8 qfA[8], qfB[8];
    {
        const float* qbase = q_g + (size_t)(b * T_ + q0 + col) * (H_ * D_)
                                 + h * D_ + half * 8;
        #pragma unroll
        for (int dchunk = 0; dchunk < 8; ++dchunk) {
            f32x8 qv = *(const f32x8*)(qbase + dchunk * 16);
            uint4 w;
            w.x = pk2(qv[0], qv[1]); w.y = pk2(qv[2], qv[3]);
            w.z = pk2(qv[4], qv[5]); w.w = pk2(qv[6], qv[7]);
            qfA[dchunk] = __builtin_bit_cast(bf16x8, w);
        }
        const float* qbase2 = qbase + (size_t)32 * (H_ * D_);
        #pragma unroll
        for (int dchunk = 0; dchunk < 8; ++dchunk) {
            f32x8 qv = *(const f32x8*)(qbase2 + dchunk * 16);
            uint4 w;
            w.x = pk2(qv[0], qv[1]); w.y = pk2(qv[2], qv[3]);
            w.z = pk2(qv[4], qv[5]); w.w = pk2(qv[6], qv[7]);
            qfB[dchunk] = __builtin_bit_cast(bf16x8, w);
        }
    }

    const u16* KFb = kf + (size_t)bh * FR_ELEMS;
    const u16* VFb = vf + (size_t)bh * FR_ELEMS;

    f32x16 accA[4] = {}, accB[4] = {};   // O[q-rows][ntile*32 + col]
    float l_A = 0.f, l_B = 0.f;          // per-lane half-row sums

    const float kexp = 0.12751744f;  // log2(e)/sqrt(128)

    // stage one 64-key K+V tile (16KB + 16KB, linear fragment-order copy):
    // 8 fire-and-forget 1KB chunks per wave (32 total, 4 waves).
    auto stage = [&](int buf, int kt) {
        const u16* ksrc = KFb + (size_t)kt * 8192;
        const u16* vsrc = VFb + (size_t)kt * 8192;
        unsigned char* base = smem + buf * SM_BUF;
        #pragma unroll
        for (int j = 0; j < 8; ++j) {
            const int idx = wave * 8 + j;              // 0..31, wave-uniform
            if (idx < 16)
                async_cp16(ksrc + idx * 512 + lane * 8, base + idx * 1024);
            else
                async_cp16(vsrc + (idx - 16) * 512 + lane * 8,
                           base + 16384 + (idx - 16) * 1024);
        }
    };

    stage(0, 0);
    __syncthreads();

    for (int kt = 0; kt < NT_; ++kt) {
        const int cur = kt & 1;
        if (kt + 1 < NT_) stage(cur ^ 1, kt + 1);      // prefetch next tile

        const unsigned char* kbuf = smem + cur * SM_BUF;
        const unsigned char* vbuf = kbuf + 16384;

        // ---- S^T = K Q^T (swapped): each K-frag read feeds 4 MFMAs (A0,A1,B0,B1)
        f32x16 sA0 = {}, sA1 = {}, sB0 = {}, sB1 = {};
        __builtin_amdgcn_s_setprio(1);
        #pragma unroll
        for (int dchunk = 0; dchunk < 8; ++dchunk) {
            bf16x8 kfr0 = *(const bf16x8*)(kbuf + dchunk * 1024 + lane * 16);
            bf16x8 kfr1 = *(const bf16x8*)(kbuf + (8 + dchunk) * 1024 + lane * 16);
            sA0 = __builtin_amdgcn_mfma_f32_32x32x16_bf16(kfr0, qfA[dchunk], sA0, 0, 0, 0);
            sA1 = __builtin_amdgcn_mfma_f32_32x32x16_bf16(kfr1, qfA[dchunk], sA1, 0, 0, 0);
            sB0 = __builtin_amdgcn_mfma_f32_32x32x16_bf16(kfr0, qfB[dchunk], sB0, 0, 0, 0);
            sB1 = __builtin_amdgcn_mfma_f32_32x32x16_bf16(kfr1, qfB[dchunk], sB1, 0, 0, 0);
        }
        __builtin_amdgcn_s_setprio(0);

        // ---- softmax (lane-local): SM(A) overlaps QK(B) tail in flight
        PA2 pA01 = softmax_pack(sA0, kexp, l_A);       // A keys  0..31 -> kc 0,1
        PA2 pA23 = softmax_pack(sA1, kexp, l_A);       // A keys 32..63 -> kc 2,3
        PA2 pB01 = softmax_pack(sB0, kexp, l_B);
        PA2 pB23 = softmax_pack(sB1, kexp, l_B);

        // ---- O += P V : each V-frag read feeds 2 MFMAs (tile A + tile B)
        __builtin_amdgcn_s_setprio(1);
        #pragma unroll
        for (int kc = 0; kc < 4; ++kc) {
            const bf16x8 pa = (kc == 0) ? pA01.f0 : (kc == 1) ? pA01.f1
                            : (kc == 2) ? pA23.f0 : pA23.f1;
            const bf16x8 pb = (kc == 0) ? pB01.f0 : (kc == 1) ? pB01.f1
                            : (kc == 2) ? pB23.f0 : pB23.f1;
            #pragma unroll
            for (int nt2 = 0; nt2 < 4; ++nt2) {
                bf16x8 vfr = *(const bf16x8*)(vbuf + (kc * 4 + nt2) * 1024 + lane * 16);
                accA[nt2] = __builtin_amdgcn_mfma_f32_32x32x16_bf16(pa, vfr, accA[nt2], 0, 0, 0);
                accB[nt2] = __builtin_amdgcn_mfma_f32_32x32x16_bf16(pb, vfr, accB[nt2], 0, 0, 0);
            }
        }
        __builtin_amdgcn_s_setprio(0);

        // single barrier/iter: drains this iter's prefetch + releases buf[cur]
        __syncthreads();
    }

    // ---- epilogue: merge half-sums, broadcast 1/l via LDS, scale, store
    const float lA_full = l_A + __shfl_xor(l_A, 32);
    const float lB_full = l_B + __shfl_xor(l_B, 32);
    float* lds_l = (float*)smem;                       // staging bufs now free
    if (half == 0) {
        lds_l[wave * 64 + col]      = 1.f / lA_full;
        lds_l[wave * 64 + 32 + col] = 1.f / lB_full;
    }
    __syncthreads();
    #pragma unroll
    for (int r = 0; r < 16; ++r) {
        const int qrow = (r & 3) + 8 * (r >> 2) + 4 * half;
        const float invA = lds_l[wave * 64 + qrow];
        const float invB = lds_l[wave * 64 + 32 + qrow];
        float* opA = o_g + (size_t)(b * T_ + q0 + qrow) * (H_ * D_) + h * D_ + col;
        float* opB = opA + (size_t)32 * (H_ * D_);
        #pragma unroll
        for (int nt2 = 0; nt2 < 4; ++nt2) {
            opA[nt2 * 32] = accA[nt2][r] * invA;
            opB[nt2 * 32] = accB[nt2][r] * invB;
        }
    }
}

// ---------------- round-4 fallback (ws too small) ----------------

#define VT_BYTES 16384
#define KT_BYTES (64 * 136 * 2)
#define PWF_BYTES 2304

__global__ __launch_bounds__(256, 2)
void gqa_fa_v1(const float* __restrict__ q_g, const float* __restrict__ k_g,
               const float* __restrict__ v_g, float* __restrict__ o_g) {
    __shared__ __align__(16) unsigned char smem[VT_BYTES + KT_BYTES + 4 * PWF_BYTES];
    unsigned char* VtB = smem;
    unsigned char* KtB = smem + VT_BYTES;
    const int lane = threadIdx.x & 63;
    const int wave = threadIdx.x >> 6;
    const int c    = lane & 15;
    const int quad = lane >> 4;
    const int qt = blockIdx.x & 31;
    const int bh = blockIdx.x >> 5;
    const int h  = bh & 15;
    const int b  = bh >> 4;
    const int q0 = qt * 64 + wave * 16;
    bf16x8 qf[4];
    {
        const float* qbase = q_g + (size_t)(b * T_ + q0 + c) * (H_ * D_) + h * D_ + quad * 8;
        #pragma unroll
        for (int dc = 0; dc < 4; ++dc) {
            f32x8 qv = *(const f32x8*)(qbase + dc * 32);
            uint4 w;
            w.x = pk2(qv[0], qv[1]); w.y = pk2(qv[2], qv[3]);
            w.z = pk2(qv[4], qv[5]); w.w = pk2(qv[6], qv[7]);
            qf[dc] = __builtin_bit_cast(bf16x8, w);
        }
    }
    f32x4 acc_o[8];
    #pragma unroll
    for (int dt = 0; dt < 8; ++dt) acc_o[dt] = (f32x4){0.f, 0.f, 0.f, 0.f};
    float m_i[4], l_i[4];
    #pragma unroll
    for (int r = 0; r < 4; ++r) { m_i[r] = -1e30f; l_i[r] = 0.f; }
    const float kexp = 0.12751744f;
    unsigned char* Pw = smem + VT_BYTES + KT_BYTES + wave * PWF_BYTES;
    const int sc0 = threadIdx.x & 15;
    const int spr = threadIdx.x >> 4;
    const size_t kvstride = (size_t)(H_ * D_);
    const float* kbase = k_g + ((size_t)b * KLEN * H_ + h) * D_;
    const float* vbase = v_g + ((size_t)b * KLEN * H_ + h) * D_;
    for (int kt = 0; kt < KLEN / 64; ++kt) {
        __syncthreads();
        #pragma unroll
        for (int i = 0; i < 4; ++i) {
            const int id   = threadIdx.x + 256 * i;
            const int row  = id >> 4;
            const int dcol = (id & 15) * 8;
            const float* kp = kbase + (size_t)(kt * 64 + row) * kvstride + dcol;
            f32x8 kv = *(const f32x8*)kp;
            uint4 w;
            w.x = pk2(kv[0], kv[1]); w.y = pk2(kv[2], kv[3]);
            w.z = pk2(kv[4], kv[5]); w.w = pk2(kv[6], kv[7]);
            *(uint4*)(KtB + (row * 136 + dcol) * 2) = w;
        }
        #pragma unroll
        for (int rr = 0; rr < 2; ++rr) {
            const int r0 = 2 * (spr + 16 * rr);
            const float* vp = vbase + (size_t)(kt * 64 + r0) * kvstride + sc0 * 8;
            f32x8 va = *(const f32x8*)vp;
            f32x8 vb = *(const f32x8*)(vp + kvstride);
            const int g_hi = r0 >> 3;
            const int woff = (r0 & 7) * 2;
            #pragma unroll
            for (int j = 0; j < 8; ++j) {
                const int d = sc0 * 8 + j;
                const int g = g_hi ^ ((d ^ (d >> 3)) & 7);
                *(u32a*)(VtB + d * 128 + g * 16 + woff) = pk2(va[j], vb[j]);
            }
        }
        __syncthreads();
        f32x4 s[4];
        #pragma unroll
        for (int nt = 0; nt < 4; ++nt) {
            s[nt] = (f32x4){0.f, 0.f, 0.f, 0.f};
            const u16* kfp = (const u16*)KtB + (nt * 16 + c) * 136 + quad * 8;
            #pragma unroll
            for (int dc = 0; dc < 4; ++dc) {
                bf16x8 kfr = *(const bf16x8*)(kfp + dc * 32);
                s[nt] = __builtin_amdgcn_mfma_f32_16x16x32_bf16(qf[dc], kfr, s[nt], 0, 0, 0);
            }
        }
        #pragma unroll
        for (int r = 0; r < 4; ++r) {
            float v = fmaxf(fmaxf(s[0][r], s[1][r]), fmaxf(s[2][r], s[3][r]));
            v = fmaxf(v, __shfl_xor(v, 1));
            v = fmaxf(v, __shfl_xor(v, 2));
            v = fmaxf(v, __shfl_xor(v, 4));
            v = fmaxf(v, __shfl_xor(v, 8));
            const float mnew  = fmaxf(m_i[r], v);
            const float alpha = exp2f((m_i[r] - mnew) * kexp);
            m_i[r] = mnew;
            l_i[r] *= alpha;
            #pragma unroll
            for (int dt = 0; dt < 8; ++dt) acc_o[dt][r] *= alpha;
            float sum = 0.f;
            #pragma unroll
            for (int nt = 0; nt < 4; ++nt) {
                const float p = exp2f((s[nt][r] - mnew) * kexp);
                sum += p;
                *(u16a*)(Pw + ((quad * 4 + r) * 72 + nt * 16 + c) * 2) = f2bf(p);
            }
            float t = sum;
            t += __shfl_xor(t, 1);
            t += __shfl_xor(t, 2);
            t += __shfl_xor(t, 4);
            t += __shfl_xor(t, 8);
            l_i[r] += t;
        }
        __syncthreads();
        #pragma unroll
        for (int kc = 0; kc < 2; ++kc) {
            bf16x8 pf = *(const bf16x8*)(Pw + (c * 72 + kc * 32 + quad * 8) * 2);
            const int k0 = kc * 32 + quad * 8;
            #pragma unroll
            for (int dt = 0; dt < 8; ++dt) {
                const int d = dt * 16 + c;
                const int g = (k0 >> 3) ^ ((d ^ (d >> 3)) & 7);
                bf16x8 vfr = *(const bf16x8*)(VtB + d * 128 + g * 16);
                acc_o[dt] = __builtin_amdgcn_mfma_f32_16x16x32_bf16(pf, vfr, acc_o[dt], 0, 0, 0);
            }
        }
    }
    #pragma unroll
    for (int r = 0; r < 4; ++r) {
        const float inv = 1.f / l_i[r];
        const int qrow = q0 + quad * 4 + r;
        float* op = o_g + (size_t)(b * T_ + qrow) * (H_ * D_) + h * D_ + c;
        #pragma unroll
        for (int dt = 0; dt < 8; ++dt)
            op[dt * 16] = acc_o[dt][r] * inv;
    }
}

extern "C" void kernel_launch(void* const* d_in, const int* in_sizes, int n_in,
                              void* d_out, int out_size, void* d_ws, size_t ws_size,
                              hipStream_t stream) {
    const float* q = (const float*)d_in[0];
    const float* k = (const float*)d_in[1];
    const float* v = (const float*)d_in[2];
    float* o = (float*)d_out;
    if (ws_size >= WS_NEED) {
        u16* kfb = (u16*)d_ws;
        u16* vfb = kfb + (size_t)BH_ * FR_ELEMS;
        prep_fused<<<dim3(1024), dim3(256), 0, stream>>>(k, v, kfb, vfb);
        gqa_fa7<<<dim3(256), dim3(256), 0, stream>>>(q, kfb, vfb, o);
    } else {
        gqa_fa_v1<<<dim3(1024), dim3(256), 0, stream>>>(q, k, v, o);
    }
}

// Round 7
// 204.811 us; speedup vs baseline: 1.1614x; 1.1614x over previous
//
#include <hip/hip_runtime.h>

// Dense MHA per head: B=2, T=2048, K=2048, H=16, D=128, fp32 in/out, bf16 MFMA.
// Round 14: T15 deferred-finish pipeline on the M=32 8-wave structure.
//   r13 post-mortem: M=64 @ 1 wave/SIMD = 137us (VGPR 228, occ 11%) --
//   latency exposure beat the LDS saving; reverted per pre-commitment.
//   fa5 model: per CU-iter 7680 cyc; matrix 2048 (27%) + LDS ~3600 (47%) +
//   VALU/trans ~3450 (45%, 32 v_exp_f32/wave-iter) = 120% -> pipes serialized
//   by the intra-wave QK->softmax->PV dependency chain (r12 proved it is not
//   barrier lockstep). Fix: iteration kt computes QK(kt) but softmax+PV of
//   tile kt-1 -- softmax VALU fills QK's MFMA/LDS shadows. Needs 3 LDS
//   buffers (K(kt), V(kt-1), prefetch kt+1) = 96KB, 1 block/CU, 8 waves.
//   S-state carried in registers with static swap (+32 VGPR).
// Workspace (fragment-ordered bf16):
//   kf[bh][kt64][ktile(2)][dchunk(8)][lane(64)][8]  (QK A-frag order)
//   vf[bh][kt64][kc(4)][ntile(4)][lane(64)][8]      (PV B-frag order)
// Fallback (ws too small): round-4 kernel (reads raw K/V, passing).

#define T_   2048
#define KLEN 2048
#define H_   16
#define D_   128
#define BH_  32
#define NT_  (KLEN / 64)

typedef unsigned short u16;
typedef short bf16x8 __attribute__((ext_vector_type(8), may_alias));
typedef float f32x4 __attribute__((ext_vector_type(4)));
typedef float f32x8 __attribute__((ext_vector_type(8), may_alias));
typedef float f32x16 __attribute__((ext_vector_type(16)));
typedef unsigned int u32a __attribute__((may_alias));
typedef u16 u16a __attribute__((may_alias));

__device__ __forceinline__ u16 f2bf(float f) {
    unsigned int u = __builtin_bit_cast(unsigned int, f);
    u += 0x7fffu + ((u >> 16) & 1u);   // RNE
    return (u16)(u >> 16);
}
// packed f32x2 -> bf16x2 (RNE), lo = a, hi = b. One VALU op.
__device__ __forceinline__ unsigned int pk2(float a, float b) {
    unsigned int r;
    asm("v_cvt_pk_bf16_f32 %0, %1, %2" : "=v"(r) : "v"(a), "v"(b));
    return r;
}
// v_permlane32_swap_b32: a.hi-lanes <-> b.lo-lanes.
// After: a = {a.lo, b.lo(shifted to hi)}, b = {a.hi(shifted to lo), b.hi}.
__device__ __forceinline__ void pl_swap(unsigned int& a, unsigned int& b) {
    asm("v_permlane32_swap_b32 %0, %1" : "+v"(a), "+v"(b));
}

// async 16B/lane global->LDS: gptr per-lane, LDS dest = uniform base + lane*16
__device__ __forceinline__ void async_cp16(const void* g, void* l) {
    __builtin_amdgcn_global_load_lds(
        (const __attribute__((address_space(1))) unsigned int*)g,
        (__attribute__((address_space(3))) unsigned int*)l, 16, 0, 0);
}

#define FR_ELEMS ((size_t)KLEN * D_)                  /* 262144 per bh */
#define WS_NEED  (2 * BH_ * FR_ELEMS * sizeof(u16))   /* 33.6 MB       */
#define SM_BUF   32768                                /* K 16KB + V 16KB */

// ---------------- fused prep: one block per (bh, kt64) ----------------
// K: QK A-frag (32x32x16): octet (ktile,dchunk,lane) holds
//   K[kt64*64 + ktile*32 + (l&31)][dchunk*16 + (l>>5)*8 + j], linear out.
// V: PV B-frag (32x32x16): octet (kc,ntile,lane) holds
//   V[kt64*64 + kc*16 + (l>>5)*8 + j][ntile*32 + (l&31)], via LDS transpose.
__global__ __launch_bounds__(256)
void prep_fused(const float* __restrict__ k_g, const float* __restrict__ v_g,
                u16* __restrict__ kf, u16* __restrict__ vf) {
    __shared__ __align__(16) unsigned char smk[16384];
    __shared__ __align__(16) unsigned char smv[16384];
    const int kt64 = blockIdx.x & 31;
    const int bh   = blockIdx.x >> 5;
    const int b = bh >> 4, h = bh & 15;
    const int tid = threadIdx.x;

    // ---- K stage: 4 consecutive rows per wave (512B segments), bf16 pack,
    //      LDS row = key*256B, 16B granule XOR-swizzled by (row & 15).
    {
        const float* kbase = k_g + ((size_t)(b * KLEN + kt64 * 64) * H_ + h) * D_;
        #pragma unroll
        for (int i = 0; i < 4; ++i) {
            const int gid  = tid + 256 * i;
            const int row  = gid >> 4;          // 0..63 tile-local key
            const int col8 = gid & 15;          // d-octet index
            f32x8 kv = *(const f32x8*)(kbase + (size_t)row * (H_ * D_) + col8 * 8);
            uint4 w;
            w.x = pk2(kv[0], kv[1]); w.y = pk2(kv[2], kv[3]);
            w.z = pk2(kv[4], kv[5]); w.w = pk2(kv[6], kv[7]);
            *(uint4*)(smk + row * 256 + ((col8 ^ (row & 15)) * 16)) = w;
        }
    }
    // ---- V stage: transposed into smv (r10-verified XOR scheme)
    {
        const float* vbase = v_g + ((size_t)b * KLEN * H_ + h) * D_;
        const int sc0 = tid & 15;
        const int spr = tid >> 4;
        #pragma unroll
        for (int rr = 0; rr < 2; ++rr) {
            const int r0 = 2 * (spr + 16 * rr);            // even tile-local key
            const float* vp = vbase + (size_t)(kt64 * 64 + r0) * (H_ * D_) + sc0 * 8;
            f32x8 va = *(const f32x8*)vp;
            f32x8 vb = *(const f32x8*)(vp + H_ * D_);
            const int g_hi = r0 >> 3;
            const int woff = (r0 & 7) * 2;
            #pragma unroll
            for (int j = 0; j < 8; ++j) {
                const int d = sc0 * 8 + j;
                const int g = g_hi ^ ((d ^ (d >> 3)) & 7);
                *(u32a*)(smv + d * 128 + g * 16 + woff) = pk2(va[j], vb[j]);
            }
        }
    }
    __syncthreads();
    // ---- K readout -> kf (16B/thread, fully coalesced)
    {
        u16* obase = kf + (size_t)bh * FR_ELEMS + (size_t)kt64 * 8192;
        #pragma unroll
        for (int i = 0; i < 4; ++i) {
            const int gid    = tid + 256 * i;    // 0..1023 octets
            const int lane   = gid & 63;
            const int dchunk = (gid >> 6) & 7;
            const int ktile  = gid >> 9;
            const int key  = ktile * 32 + (lane & 31);
            const int col8 = dchunk * 2 + (lane >> 5);
            uint4 w = *(const uint4*)(smk + key * 256 + ((col8 ^ (key & 15)) * 16));
            *(uint4*)(obase + (size_t)gid * 8) = w;
        }
    }
    // ---- V readout -> vf (r10-verified)
    {
        u16* obase = vf + (size_t)bh * FR_ELEMS;
        #pragma unroll
        for (int i = 0; i < 4; ++i) {
            const int gid   = tid + 256 * i;
            const int lane  = gid & 63;
            const int ntile = (gid >> 6) & 3;
            const int kc    = (gid >> 8) & 3;
            const int key0  = kc * 16 + (lane >> 5) * 8;   // tile-local, %8==0
            const int d     = ntile * 32 + (lane & 31);
            const int g     = (key0 >> 3) ^ ((d ^ (d >> 3)) & 7);
            uint4 w = *(const uint4*)(smv + d * 128 + g * 16);
            *(uint4*)(obase + ((size_t)(kt64 * 16 + kc * 4 + ntile) * 64 + lane) * 8) = w;
        }
    }
}

// ---------------- main kernel: swapped-QK 32x32, deferred softmax/PV ----------------

struct PA2 { bf16x8 f0, f1; };   // A-frags for two 16-key PV chunks

__device__ __forceinline__ PA2 softmax_pack(f32x16 st, float kexp, float& lacc) {
    float p[16];
    #pragma unroll
    for (int r = 0; r < 16; ++r) p[r] = exp2f(st[r] * kexp);
    lacc += (((p[0] + p[1]) + (p[2] + p[3])) + ((p[4] + p[5]) + (p[6] + p[7])))
          + (((p[8] + p[9]) + (p[10] + p[11])) + ((p[12] + p[13]) + (p[14] + p[15])));
    // reg r holds P[q=lane&31][key kl=(r&3)+8*(r>>2)+4*half] (m74/m101 C-layout).
    // A-frag needs lane(half,q): P[q][k = half*8 + j]. Pack pairs then swap
    // halves: out_a = {a.lo, b.lo}, out_b = {a.hi, b.hi} (see pl_swap).
    unsigned int a0 = pk2(p[0], p[1]),   b0 = pk2(p[4], p[5]);
    unsigned int a1 = pk2(p[2], p[3]),   b1 = pk2(p[6], p[7]);
    unsigned int a2 = pk2(p[8], p[9]),   b2 = pk2(p[12], p[13]);
    unsigned int a3 = pk2(p[10], p[11]), b3 = pk2(p[14], p[15]);
    pl_swap(a0, b0); pl_swap(a1, b1); pl_swap(a2, b2); pl_swap(a3, b3);
    uint4 w0; w0.x = a0; w0.y = a1; w0.z = b0; w0.w = b1;   // keys 0..15
    uint4 w1; w1.x = a2; w1.y = a3; w1.z = b2; w1.w = b3;   // keys 16..31
    PA2 r;
    r.f0 = __builtin_bit_cast(bf16x8, w0);
    r.f1 = __builtin_bit_cast(bf16x8, w1);
    return r;
}

__global__ __launch_bounds__(512, 2)
void gqa_fa8(const float* __restrict__ q_g, const u16* __restrict__ kf,
             const u16* __restrict__ vf, float* __restrict__ o_g) {
    __shared__ __align__(16) unsigned char smem[3 * SM_BUF];   // 96 KB, 3-deep

    const int lane = threadIdx.x & 63;
    const int wave = threadIdx.x >> 6;        // 0..7
    const int half = lane >> 5;
    const int col  = lane & 31;

    // grid 256 = 1 block/CU; XCD swizzle: bh = xcd*4 + j, 8 qt blocks per bh
    const int blk = blockIdx.x;
    const int bh  = (blk & 7) * 4 + (blk >> 6);
    const int qt  = (blk >> 3) & 7;
    const int b = bh >> 4, h = bh & 15;

    const int q0 = qt * 256 + wave * 32;      // this wave: rows q0 .. q0+31

    // Q B-frag (32x32x16): lane holds Q[q0+col][dchunk*16 + half*8 + j]
    bf16x8 qf[8];
    {
        const float* qbase = q_g + (size_t)(b * T_ + q0 + col) * (H_ * D_)
                                 + h * D_ + half * 8;
        #pragma unroll
        for (int dchunk = 0; dchunk < 8; ++dchunk) {
            f32x8 qv = *(const f32x8*)(qbase + dchunk * 16);
            uint4 w;
            w.x = pk2(qv[0], qv[1]); w.y = pk2(qv[2], qv[3]);
            w.z = pk2(qv[4], qv[5]); w.w = pk2(qv[6], qv[7]);
            qf[dchunk] = __builtin_bit_cast(bf16x8, w);
        }
    }

    const u16* KFb = kf + (size_t)bh * FR_ELEMS;
    const u16* VFb = vf + (size_t)bh * FR_ELEMS;

    f32x16 acc[4] = {};          // O[q-rows][ntile*32 + col]
    float l_part = 0.f;          // per-lane half-row sum; merged in epilogue

    const float kexp = 0.12751744f;  // log2(e)/sqrt(128)

    // stage one 64-key K+V tile (16KB + 16KB, linear fragment-order copy):
    // 4 fire-and-forget 1KB chunks per wave (32 total, 8 waves).
    auto stage = [&](int buf, int kt) {
        const u16* ksrc = KFb + (size_t)kt * 8192;
        const u16* vsrc = VFb + (size_t)kt * 8192;
        unsigned char* base = smem + buf * SM_BUF;
        #pragma unroll
        for (int j = 0; j < 4; ++j) {
            const int idx = wave * 4 + j;              // 0..31, wave-uniform
            if (idx < 16)
                async_cp16(ksrc + idx * 512 + lane * 8, base + idx * 1024);
            else
                async_cp16(vsrc + (idx - 16) * 512 + lane * 8,
                           base + 16384 + (idx - 16) * 1024);
        }
    };

    // QK for one tile: 16 ds_read_b128 + 16 MFMA into (d0,d1)
    auto qk_tile = [&](const unsigned char* kbuf, f32x16& d0, f32x16& d1) {
        __builtin_amdgcn_s_setprio(1);
        #pragma unroll
        for (int dchunk = 0; dchunk < 8; ++dchunk) {
            bf16x8 kfr0 = *(const bf16x8*)(kbuf + dchunk * 1024 + lane * 16);
            bf16x8 kfr1 = *(const bf16x8*)(kbuf + (8 + dchunk) * 1024 + lane * 16);
            d0 = __builtin_amdgcn_mfma_f32_32x32x16_bf16(kfr0, qf[dchunk], d0, 0, 0, 0);
            d1 = __builtin_amdgcn_mfma_f32_32x32x16_bf16(kfr1, qf[dchunk], d1, 0, 0, 0);
        }
        __builtin_amdgcn_s_setprio(0);
    };

    // softmax + PV for the PREVIOUS tile's S (t0,t1), V from vbuf
    auto sm_pv = [&](f32x16 t0, f32x16 t1, const unsigned char* vbuf) {
        PA2 pa01 = softmax_pack(t0, kexp, l_part);     // keys  0..31 -> kc 0,1
        PA2 pa23 = softmax_pack(t1, kexp, l_part);     // keys 32..63 -> kc 2,3
        __builtin_amdgcn_s_setprio(1);
        #pragma unroll
        for (int kc = 0; kc < 4; ++kc) {
            const bf16x8 paf = (kc == 0) ? pa01.f0 : (kc == 1) ? pa01.f1
                             : (kc == 2) ? pa23.f0 : pa23.f1;
            #pragma unroll
            for (int nt2 = 0; nt2 < 4; ++nt2) {
                bf16x8 vfr = *(const bf16x8*)(vbuf + (kc * 4 + nt2) * 1024 + lane * 16);
                acc[nt2] = __builtin_amdgcn_mfma_f32_32x32x16_bf16(paf, vfr, acc[nt2], 0, 0, 0);
            }
        }
        __builtin_amdgcn_s_setprio(0);
    };

    // ---- prologue: tile 0 staged+computed (QK only; its SM/PV is deferred)
    stage(0, 0);
    __syncthreads();                 // tile 0 resident
    stage(1, 1);                     // prefetch tile 1
    f32x16 ps0 = {}, ps1 = {};       // carried S of tile kt-1
    qk_tile(smem, ps0, ps1);
    __syncthreads();                 // tile 1 resident; all waves done QK(0)

    int cur = 1, prev = 0;
    for (int kt = 1; kt < NT_; ++kt) {
        const int nxt = (cur == 2) ? 0 : cur + 1;
        if (kt + 1 < NT_) stage(nxt, kt + 1);          // prefetch kt+1

        // QK(kt) issues first; softmax(kt-1) VALU fills its MFMA/LDS shadows.
        f32x16 ns0 = {}, ns1 = {};
        qk_tile(smem + cur * SM_BUF, ns0, ns1);
        sm_pv(ps0, ps1, smem + prev * SM_BUF + 16384);

        ps0 = ns0; ps1 = ns1;        // static swap (no runtime indexing)
        prev = cur; cur = nxt;
        // barrier: drains prefetch (vmcnt) + releases buf being overwritten next
        __syncthreads();
    }
    // ---- tail: softmax+PV of the last tile (V still resident in buf prev)
    sm_pv(ps0, ps1, smem + prev * SM_BUF + 16384);

    // ---- epilogue: merge half-sums, broadcast 1/l via LDS, scale, store
    const float l_full = l_part + __shfl_xor(l_part, 32);
    float* lds_l = (float*)smem;                       // [0,1KB) - no V overlap
    if (half == 0) lds_l[wave * 32 + col] = 1.f / l_full;
    __syncthreads();
    #pragma unroll
    for (int r = 0; r < 16; ++r) {
        const int qrow = (r & 3) + 8 * (r >> 2) + 4 * half;
        const float inv = lds_l[wave * 32 + qrow];
        float* op = o_g + (size_t)(b * T_ + q0 + qrow) * (H_ * D_) + h * D_ + col;
        #pragma unroll
        for (int nt2 = 0; nt2 < 4; ++nt2)
            op[nt2 * 32] = acc[nt2][r] * inv;
    }
}

// ---------------- round-4 fallback (ws too small) ----------------

#define VT_BYTES 16384
#define KT_BYTES (64 * 136 * 2)
#define PWF_BYTES 2304

__global__ __launch_bounds__(256, 2)
void gqa_fa_v1(const float* __restrict__ q_g, const float* __restrict__ k_g,
               const float* __restrict__ v_g, float* __restrict__ o_g) {
    __shared__ __align__(16) unsigned char smem[VT_BYTES + KT_BYTES + 4 * PWF_BYTES];
    unsigned char* VtB = smem;
    unsigned char* KtB = smem + VT_BYTES;
    const int lane = threadIdx.x & 63;
    const int wave = threadIdx.x >> 6;
    const int c    = lane & 15;
    const int quad = lane >> 4;
    const int qt = blockIdx.x & 31;
    const int bh = blockIdx.x >> 5;
    const int h  = bh & 15;
    const int b  = bh >> 4;
    const int q0 = qt * 64 + wave * 16;
    bf16x8 qf[4];
    {
        const float* qbase = q_g + (size_t)(b * T_ + q0 + c) * (H_ * D_) + h * D_ + quad * 8;
        #pragma unroll
        for (int dc = 0; dc < 4; ++dc) {
            f32x8 qv = *(const f32x8*)(qbase + dc * 32);
            uint4 w;
            w.x = pk2(qv[0], qv[1]); w.y = pk2(qv[2], qv[3]);
            w.z = pk2(qv[4], qv[5]); w.w = pk2(qv[6], qv[7]);
            qf[dc] = __builtin_bit_cast(bf16x8, w);
        }
    }
    f32x4 acc_o[8];
    #pragma unroll
    for (int dt = 0; dt < 8; ++dt) acc_o[dt] = (f32x4){0.f, 0.f, 0.f, 0.f};
    float m_i[4], l_i[4];
    #pragma unroll
    for (int r = 0; r < 4; ++r) { m_i[r] = -1e30f; l_i[r] = 0.f; }
    const float kexp = 0.12751744f;
    unsigned char* Pw = smem + VT_BYTES + KT_BYTES + wave * PWF_BYTES;
    const int sc0 = threadIdx.x & 15;
    const int spr = threadIdx.x >> 4;
    const size_t kvstride = (size_t)(H_ * D_);
    const float* kbase = k_g + ((size_t)b * KLEN * H_ + h) * D_;
    const float* vbase = v_g + ((size_t)b * KLEN * H_ + h) * D_;
    for (int kt = 0; kt < KLEN / 64; ++kt) {
        __syncthreads();
        #pragma unroll
        for (int i = 0; i < 4; ++i) {
            const int id   = threadIdx.x + 256 * i;
            const int row  = id >> 4;
            const int dcol = (id & 15) * 8;
            const float* kp = kbase + (size_t)(kt * 64 + row) * kvstride + dcol;
            f32x8 kv = *(const f32x8*)kp;
            uint4 w;
            w.x = pk2(kv[0], kv[1]); w.y = pk2(kv[2], kv[3]);
            w.z = pk2(kv[4], kv[5]); w.w = pk2(kv[6], kv[7]);
            *(uint4*)(KtB + (row * 136 + dcol) * 2) = w;
        }
        #pragma unroll
        for (int rr = 0; rr < 2; ++rr) {
            const int r0 = 2 * (spr + 16 * rr);
            const float* vp = vbase + (size_t)(kt * 64 + r0) * kvstride + sc0 * 8;
            f32x8 va = *(const f32x8*)vp;
            f32x8 vb = *(const f32x8*)(vp + kvstride);
            const int g_hi = r0 >> 3;
            const int woff = (r0 & 7) * 2;
            #pragma unroll
            for (int j = 0; j < 8; ++j) {
                const int d = sc0 * 8 + j;
                const int g = g_hi ^ ((d ^ (d >> 3)) & 7);
                *(u32a*)(VtB + d * 128 + g * 16 + woff) = pk2(va[j], vb[j]);
            }
        }
        __syncthreads();
        f32x4 s[4];
        #pragma unroll
        for (int nt = 0; nt < 4; ++nt) {
            s[nt] = (f32x4){0.f, 0.f, 0.f, 0.f};
            const u16* kfp = (const u16*)KtB + (nt * 16 + c) * 136 + quad * 8;
            #pragma unroll
            for (int dc = 0; dc < 4; ++dc) {
                bf16x8 kfr = *(const bf16x8*)(kfp + dc * 32);
                s[nt] = __builtin_amdgcn_mfma_f32_16x16x32_bf16(qf[dc], kfr, s[nt], 0, 0, 0);
            }
        }
        #pragma unroll
        for (int r = 0; r < 4; ++r) {
            float v = fmaxf(fmaxf(s[0][r], s[1][r]), fmaxf(s[2][r], s[3][r]));
            v = fmaxf(v, __shfl_xor(v, 1));
            v = fmaxf(v, __shfl_xor(v, 2));
            v = fmaxf(v, __shfl_xor(v, 4));
            v = fmaxf(v, __shfl_xor(v, 8));
            const float mnew  = fmaxf(m_i[r], v);
            const float alpha = exp2f((m_i[r] - mnew) * kexp);
            m_i[r] = mnew;
            l_i[r] *= alpha;
            #pragma unroll
            for (int dt = 0; dt < 8; ++dt) acc_o[dt][r] *= alpha;
            float sum = 0.f;
            #pragma unroll
            for (int nt = 0; nt < 4; ++nt) {
                const float p = exp2f((s[nt][r] - mnew) * kexp);
                sum += p;
                *(u16a*)(Pw + ((quad * 4 + r) * 72 + nt * 16 + c) * 2) = f2bf(p);
            }
            float t = sum;
            t += __shfl_xor(t, 1);
            t += __shfl_xor(t, 2);
            t += __shfl_xor(t, 4);
            t += __shfl_xor(t, 8);
            l_i[r] += t;
        }
        __syncthreads();
        #pragma unroll
        for (int kc = 0; kc < 2; ++kc) {
            bf16x8 pf = *(const bf16x8*)(Pw + (c * 72 + kc * 32 + quad * 8) * 2);
            const int k0 = kc * 32 + quad * 8;
            #pragma unroll
            for (int dt = 0; dt < 8; ++dt) {
                const int d = dt * 16 + c;
                const int g = (k0 >> 3) ^ ((d ^ (d >> 3)) & 7);
                bf16x8 vfr = *(const bf16x8*)(VtB + d * 128 + g * 16);
                acc_o[dt] = __builtin_amdgcn_mfma_f32_16x16x32_bf16(pf, vfr, acc_o[dt], 0, 0, 0);
            }
        }
    }
    #pragma unroll
    for (int r = 0; r < 4; ++r) {
        const float inv = 1.f / l_i[r];
        const int qrow = q0 + quad * 4 + r;
        float* op = o_g + (size_t)(b * T_ + qrow) * (H_ * D_) + h * D_ + c;
        #pragma unroll
        for (int dt = 0; dt < 8; ++dt)
            op[dt * 16] = acc_o[dt][r] * inv;
    }
}

extern "C" void kernel_launch(void* const* d_in, const int* in_sizes, int n_in,
                              void* d_out, int out_size, void* d_ws, size_t ws_size,
                              hipStream_t stream) {
    const float* q = (const float*)d_in[0];
    const float* k = (const float*)d_in[1];
    const float* v = (const float*)d_in[2];
    float* o = (float*)d_out;
    if (ws_size >= WS_NEED) {
        u16* kfb = (u16*)d_ws;
        u16* vfb = kfb + (size_t)BH_ * FR_ELEMS;
        prep_fused<<<dim3(1024), dim3(256), 0, stream>>>(k, v, kfb, vfb);
        gqa_fa8<<<dim3(256), dim3(512), 0, stream>>>(q, kfb, vfb, o);
    } else {
        gqa_fa_v1<<<dim3(1024), dim3(256), 0, stream>>>(q, k, v, o);
    }
}